// Round 5
// baseline (580.140 us; speedup 1.0000x reference)
//
#include <hip/hip_runtime.h>
#include <stdint.h>

// ---------------------------------------------------------------------------
// MultiHeadAdaptiveChebyshevLayer, round 7: two-pass recompute, no y array.
// Calibrated model: fixed tax/iter ~212 us (1 GiB ws poison 165.7 + out
// poison ~42 + prologs ~4).  Main kernel history: R0=109 (128-cap, 1 blk/CU),
// R2=210 (64-cap, 64-word spill), R3=156 (512-cap, 1 blk/CU), R4=144
// (64-cap, y2[32] partial spill).  Lesson: 2 blocks/CU requires <=64 VGPR
// *without* the 32-reg y2 array -> recompute y in a second pass instead of
// storing it.  2 rows/block keeps total W3 L2 traffic at R0's level
// (pass1+pass2 shared by both rows = 2 MiB / 2 rows = 1 MiB/row).
//
// Per-CU pipe estimate: VALU ~28 us, L2 ~35 us, HBM-store ~42 us; 2 resident
// blocks in different phases overlap them (1 block/CU serializes -> R0's 109).
//
// Ownership (per row): thread t owns features f = c*4096 + t*4 + {0..3};
// p = c*512 + (t>>1), k = (t&1)*4 + d.  W3[(c*4+d)*1024 + t] is the folded
// bf16x8 coeff vector for feature d; GB3[c*1024+t] packs gamma/beta.
// ---------------------------------------------------------------------------

#define LN_EPS 1e-5f

typedef float vfloat4 __attribute__((ext_vector_type(4)));

__device__ __forceinline__ unsigned bf16_rne(float f) {
    unsigned u = __float_as_uint(f);
    unsigned r = u + 0x7fffu + ((u >> 16) & 1u);
    return r >> 16;
}
__device__ __forceinline__ float bf_lo(unsigned u) { return __uint_as_float(u << 16); }
__device__ __forceinline__ float bf_hi(unsigned u) { return __uint_as_float(u & 0xffff0000u); }

// Prologue 1: fold poly into kernel, bf16-pack over m, permute so the main
// kernel's load for (c,d) at lane t is W3[(c*4+d)*1024 + t].
__global__ void fold_weights_kernel(const float* __restrict__ K,
                                    const float* __restrict__ poly,
                                    uint4* __restrict__ W3) {
    int tid = blockIdx.x * blockDim.x + threadIdx.x;   // [0, 65536)
    int p = tid >> 3, k = tid & 7;
    const float* kp = K + (size_t)p * 64 + k;          // stride 8 over m
    float pw = poly[p * 8 + k];
    float v[8];
#pragma unroll
    for (int m = 0; m < 8; ++m) v[m] = kp[m * 8] * pw;
    uint4 q;
    q.x = bf16_rne(v[0]) | (bf16_rne(v[1]) << 16);
    q.y = bf16_rne(v[2]) | (bf16_rne(v[3]) << 16);
    q.z = bf16_rne(v[4]) | (bf16_rne(v[5]) << 16);
    q.w = bf16_rne(v[6]) | (bf16_rne(v[7]) << 16);
    int c = p >> 9;
    int t = ((p & 511) << 1) | (k >> 2);
    int d = k & 3;
    W3[(c * 4 + d) * 1024 + t] = q;
}

// Prologue 2: GB3[tid] covers features f = tid*4 .. +3; each word packs
// (bf16(gamma) | bf16(beta)<<16).
__global__ void pack_gb_kernel(const float* __restrict__ gamma,
                               const float* __restrict__ beta,
                               uint4* __restrict__ GB3) {
    int tid = blockIdx.x * blockDim.x + threadIdx.x;   // [0, 16384)
    float4 g = ((const float4*)gamma)[tid];
    float4 b = ((const float4*)beta)[tid];
    uint4 q;
    q.x = bf16_rne(g.x) | (bf16_rne(b.x) << 16);
    q.y = bf16_rne(g.y) | (bf16_rne(b.y) << 16);
    q.z = bf16_rne(g.z) | (bf16_rne(b.z) << 16);
    q.w = bf16_rne(g.w) | (bf16_rne(b.w) << 16);
    GB3[tid] = q;
}

// Shared-unpack dot: 8 bf16 coeffs from q feed BOTH rows' accumulators.
// Requires Ta1..Ta7 / Tb1..Tb7 in scope.
#define CHEB_DOT2(q, accA, accB)                                              \
    {                                                                         \
        float c0 = bf_lo(q.x), c1 = bf_hi(q.x);                               \
        float c2 = bf_lo(q.y), c3 = bf_hi(q.y);                               \
        float c4 = bf_lo(q.z), c5 = bf_hi(q.z);                               \
        float c6 = bf_lo(q.w), c7 = bf_hi(q.w);                               \
        accA = fmaf(Ta1, c1, c0);   accB = fmaf(Tb1, c1, c0);                 \
        accA = fmaf(Ta2, c2, accA); accB = fmaf(Tb2, c2, accB);               \
        accA = fmaf(Ta3, c3, accA); accB = fmaf(Tb3, c3, accB);               \
        accA = fmaf(Ta4, c4, accA); accB = fmaf(Tb4, c4, accB);               \
        accA = fmaf(Ta5, c5, accA); accB = fmaf(Tb5, c5, accB);               \
        accA = fmaf(Ta6, c6, accA); accB = fmaf(Tb6, c6, accB);               \
        accA = fmaf(Ta7, c7, accA); accB = fmaf(Tb7, c7, accB);               \
    }

// Chebyshev T1..T7 for both rows from xs values va, vb.
#define CHEB_TERMS(va, vb)                                                    \
    float va2 = va + va, vb2 = vb + vb;                                       \
    float Ta1 = va, Tb1 = vb;                                                 \
    float Ta2 = fmaf(va2, Ta1, -1.f),  Tb2 = fmaf(vb2, Tb1, -1.f);            \
    float Ta3 = fmaf(va2, Ta2, -Ta1), Tb3 = fmaf(vb2, Tb2, -Tb1);             \
    float Ta4 = fmaf(va2, Ta3, -Ta2), Tb4 = fmaf(vb2, Tb3, -Tb2);             \
    float Ta5 = fmaf(va2, Ta4, -Ta3), Tb5 = fmaf(vb2, Tb4, -Tb3);             \
    float Ta6 = fmaf(va2, Ta5, -Ta4), Tb6 = fmaf(vb2, Tb5, -Tb4);             \
    float Ta7 = fmaf(va2, Ta6, -Ta5), Tb7 = fmaf(vb2, Tb6, -Tb5)

// Main: one block (1024 threads) per TWO rows; 512 blocks = 2 blocks/CU.
// Hard 64-VGPR cap via min 8 waves/EU; live set ~40 (no y array) fits.
__global__ __launch_bounds__(1024, 8) void cheb_ln_main(
    const float* __restrict__ x, const float* __restrict__ scale,
    const uint4* __restrict__ W3, const uint4* __restrict__ GB3,
    float* __restrict__ out) {
    __shared__ float xs[2][8192];
    __shared__ float red[64];
    const int r0 = blockIdx.x << 1;
    const int t = threadIdx.x;
    const int w = t >> 6, l = t & 63;
    const int phalf = t >> 1;

    // Stage xs[r][h*1024+i] = x[r][i] * scale[h][i]; scale loaded once for
    // both rows.  Coalesced; readback is 2-way same-address (free).
    float xv0 = x[(size_t)r0 * 1024 + t];
    float xv1 = x[(size_t)(r0 + 1) * 1024 + t];
#pragma unroll
    for (int h = 0; h < 8; ++h) {
        float s = scale[h * 1024 + t];
        xs[0][h * 1024 + t] = xv0 * s;
        xs[1][h * 1024 + t] = xv1 * s;
    }
    __syncthreads();

    // ---- Pass 1: sum / sumsq only (no y materialization) ----
    float sum0 = 0.f, sq0 = 0.f, sum1 = 0.f, sq1 = 0.f;
#pragma unroll
    for (int c = 0; c < 16; ++c) {
        float va = xs[0][c * 512 + phalf];
        float vb = xs[1][c * 512 + phalf];
        CHEB_TERMS(va, vb);
#pragma unroll
        for (int d = 0; d < 4; ++d) {           // one quad live at a time
            uint4 q = W3[(c * 4 + d) * 1024 + t];
            float a, b;
            CHEB_DOT2(q, a, b);
            sum0 += a; sq0 = fmaf(a, a, sq0);
            sum1 += b; sq1 = fmaf(b, b, sq1);
        }
    }

    // Wave reduce (64 lanes), then cross-wave via LDS.
#pragma unroll
    for (int off = 32; off; off >>= 1) {
        sum0 += __shfl_down(sum0, off, 64);
        sq0  += __shfl_down(sq0,  off, 64);
        sum1 += __shfl_down(sum1, off, 64);
        sq1  += __shfl_down(sq1,  off, 64);
    }
    if (l == 0) {
        red[w * 4 + 0] = sum0; red[w * 4 + 1] = sq0;
        red[w * 4 + 2] = sum1; red[w * 4 + 3] = sq1;
    }
    __syncthreads();
    float S0 = 0.f, Q0 = 0.f, S1 = 0.f, Q1 = 0.f;
#pragma unroll
    for (int q = 0; q < 16; ++q) {
        S0 += red[q * 4 + 0]; Q0 += red[q * 4 + 1];
        S1 += red[q * 4 + 2]; Q1 += red[q * 4 + 3];
    }
    const float inv = 1.f / 65536.f;
    float mu0 = S0 * inv, mu1 = S1 * inv;
    float rs0 = rsqrtf(fmaf(-mu0, mu0, Q0 * inv) + LN_EPS);
    float rs1 = rsqrtf(fmaf(-mu1, mu1, Q1 * inv) + LN_EPS);

    // ---- Pass 2: recompute y (W3 L2-hot), normalize, store both rows ----
    float* o0 = out + (size_t)r0 * 65536;
    float* o1 = o0 + 65536;
#pragma unroll
    for (int c = 0; c < 16; ++c) {
        float va = xs[0][c * 512 + phalf];
        float vb = xs[1][c * 512 + phalf];
        CHEB_TERMS(va, vb);

        float a0, a1, a2, a3, b0, b1, b2, b3;
        {
            uint4 q = W3[(c * 4 + 0) * 1024 + t];
            CHEB_DOT2(q, a0, b0);
        }
        {
            uint4 q = W3[(c * 4 + 1) * 1024 + t];
            CHEB_DOT2(q, a1, b1);
        }
        {
            uint4 q = W3[(c * 4 + 2) * 1024 + t];
            CHEB_DOT2(q, a2, b2);
        }
        {
            uint4 q = W3[(c * 4 + 3) * 1024 + t];
            CHEB_DOT2(q, a3, b3);
        }

        uint4 g = GB3[c * 1024 + t];
        vfloat4 oA;
        oA.x = fmaf((a0 - mu0) * rs0, bf_lo(g.x), bf_hi(g.x));
        oA.y = fmaf((a1 - mu0) * rs0, bf_lo(g.y), bf_hi(g.y));
        oA.z = fmaf((a2 - mu0) * rs0, bf_lo(g.z), bf_hi(g.z));
        oA.w = fmaf((a3 - mu0) * rs0, bf_lo(g.w), bf_hi(g.w));
        __builtin_nontemporal_store(oA, (vfloat4*)(o0 + c * 4096 + t * 4));
        vfloat4 oB;
        oB.x = fmaf((b0 - mu1) * rs1, bf_lo(g.x), bf_hi(g.x));
        oB.y = fmaf((b1 - mu1) * rs1, bf_lo(g.y), bf_hi(g.y));
        oB.z = fmaf((b2 - mu1) * rs1, bf_lo(g.z), bf_hi(g.z));
        oB.w = fmaf((b3 - mu1) * rs1, bf_lo(g.w), bf_hi(g.w));
        __builtin_nontemporal_store(oB, (vfloat4*)(o1 + c * 4096 + t * 4));
    }
}

extern "C" void kernel_launch(void* const* d_in, const int* in_sizes, int n_in,
                              void* d_out, int out_size, void* d_ws, size_t ws_size,
                              hipStream_t stream) {
    const float* x     = (const float*)d_in[0];   // [1024,1024]
    const float* scale = (const float*)d_in[1];   // [8,1024]
    const float* poly  = (const float*)d_in[2];   // [8,1024,8]
    const float* kern  = (const float*)d_in[3];   // [8,1024,8,8]
    const float* gamma = (const float*)d_in[4];   // [65536]
    const float* beta  = (const float*)d_in[5];   // [65536]
    float* out = (float*)d_out;

    uint4* W3  = (uint4*)d_ws;                          // 1 MiB
    uint4* GB3 = (uint4*)((char*)d_ws + (1u << 20));    // 256 KiB

    fold_weights_kernel<<<256, 256, 0, stream>>>(kern, poly, W3);
    pack_gb_kernel<<<64, 256, 0, stream>>>(gamma, beta, GB3);
    cheb_ln_main<<<512, 1024, 0, stream>>>(x, scale, W3, GB3, out);
}